// Round 17
// baseline (389.236 us; speedup 1.0000x reference)
//
#include <hip/hip_runtime.h>
#include <stdint.h>

#define S_ 1024
#define D_ 64
#define B_ 64

typedef short short8 __attribute__((ext_vector_type(8)));
typedef unsigned short ushort8 __attribute__((ext_vector_type(8)));
typedef float f32x4 __attribute__((ext_vector_type(4)));
typedef unsigned short u16;

__device__ __forceinline__ u16 f2bf(float x) {
    uint32_t u = __builtin_bit_cast(uint32_t, x);
    return (u16)((u + 0x7FFFu + ((u >> 16) & 1u)) >> 16);
}
__device__ __forceinline__ float bf2f(u16 b) {
    return __builtin_bit_cast(float, ((uint32_t)b) << 16);
}
__device__ __forceinline__ uint32_t pack2(float a, float b) {
    return (uint32_t)f2bf(a) | ((uint32_t)f2bf(b) << 16);
}
// XOR-swizzled index into a row x 512 bf16 buffer (16B-chunk swizzle by row&15)
__device__ __forceinline__ int sidx5(int row, int k) {
    return (((row << 9) + (k & ~7)) ^ ((row & 15) << 3)) + (k & 7);
}
// XOR-swizzled index into a row x 1024 bf16 buffer (fallback path)
__device__ __forceinline__ int scidx(int row, int k) {
    return (((row << 10) + (k & ~7)) ^ ((row & 15) << 3)) + (k & 7);
}

// ---------------- K1: qk[b,q,k] = (Q.K)*SCL -> bf16 ws (WS) or f32 attn region
template <int WS>
__global__ __launch_bounds__(256) void k1_qk(const float* __restrict__ Q,
                                             const float* __restrict__ Kk,
                                             float* __restrict__ qkf,
                                             u16* __restrict__ qkb) {
    __shared__ __align__(16) u16 Qs[128][72];
    __shared__ __align__(16) u16 Ks[128][72];
    const float SCL = 0.18033688011112042f;  // log2(e)/8
    const int bx = blockIdx.x;
    const int b  = bx >> 6;
    const int q0 = ((bx >> 3) & 7) << 7;
    const int k0 = (bx & 7) << 7;
    const int t  = threadIdx.x;
#pragma unroll
    for (int i = 0; i < 8; ++i) {
        int f = (i << 8) + t;
        int row = f >> 4, c = (f & 15) << 2;
        float4 v = *reinterpret_cast<const float4*>(&Q[((size_t)(b * S_ + q0 + row) << 6) + c]);
        *reinterpret_cast<uint2*>(&Qs[row][c]) = make_uint2(pack2(v.x, v.y), pack2(v.z, v.w));
        float4 u = *reinterpret_cast<const float4*>(&Kk[((size_t)(b * S_ + k0 + row) << 6) + c]);
        *reinterpret_cast<uint2*>(&Ks[row][c]) = make_uint2(pack2(u.x, u.y), pack2(u.z, u.w));
    }
    __syncthreads();
    const int l = t & 63, w = t >> 6, lr = l & 15, lg = l >> 4;
    short8 a[2][2];
#pragma unroll
    for (int mi = 0; mi < 2; ++mi)
#pragma unroll
        for (int h = 0; h < 2; ++h)
            a[mi][h] = *reinterpret_cast<const short8*>(&Qs[((w * 2 + mi) << 4) + lr][h * 32 + lg * 8]);
    f32x4 acc[2][8] = {};
#pragma unroll
    for (int n = 0; n < 8; ++n) {
        short8 b0 = *reinterpret_cast<const short8*>(&Ks[(n << 4) + lr][lg * 8]);
        short8 b1 = *reinterpret_cast<const short8*>(&Ks[(n << 4) + lr][32 + lg * 8]);
#pragma unroll
        for (int mi = 0; mi < 2; ++mi) {
            acc[mi][n] = __builtin_amdgcn_mfma_f32_16x16x32_bf16(a[mi][0], b0, acc[mi][n], 0, 0, 0);
            acc[mi][n] = __builtin_amdgcn_mfma_f32_16x16x32_bf16(a[mi][1], b1, acc[mi][n], 0, 0, 0);
        }
    }
#pragma unroll
    for (int mi = 0; mi < 2; ++mi)
#pragma unroll
        for (int n = 0; n < 8; ++n)
#pragma unroll
            for (int r = 0; r < 4; ++r) {
                int qq = q0 + ((w * 2 + mi) << 4) + (lg << 2) + r;
                int kc = k0 + (n << 4) + lr;
                size_t idx = ((size_t)(b * S_ + qq) << 10) + kc;
                if (WS) qkb[idx] = f2bf(acc[mi][n][r] * SCL);
                else    qkf[idx] = acc[mi][n][r] * SCL;
            }
}

// in-register 4x4 transpose (lanes l, l^16, l^32, l^48) then b64 store: T[d][kb..kb+3]
__device__ __forceinline__ void tpose_store_p(u16* Tls, int pitch, float4 p,
                                              int kb, int t) {
    const int l = t & 63, lr = l & 15, lg = l >> 4;
    float v0 = p.x, v1 = p.y, v2 = p.z, v3 = p.w;
    float y0 = __shfl_xor(v0, 16), y1 = __shfl_xor(v1, 16),
          y2 = __shfl_xor(v2, 16), y3 = __shfl_xor(v3, 16);
    bool o = (lg & 1);
    float n0 = o ? y1 : v0, n1 = o ? v1 : y0, n2 = o ? y3 : v2, n3 = o ? v3 : y2;
    float z0 = __shfl_xor(n0, 32), z1 = __shfl_xor(n1, 32),
          z2 = __shfl_xor(n2, 32), z3 = __shfl_xor(n3, 32);
    bool h = (lg & 2);
    float T0 = h ? z2 : n0, T1 = h ? z3 : n1, T2 = h ? n2 : z0, T3 = h ? n3 : z1;
    int d = (lr << 2) + lg;
    *reinterpret_cast<uint2*>(&Tls[d * pitch + kb]) = make_uint2(pack2(T0, T1), pack2(T2, T3));
}

// ---------------- K2 (WS=1): one block per q, 512 threads, ~73 KB LDS -> 2 blocks/CU
// k split in 2 halves; combine per half writes P straight to global; phase B reads P
// fragments from global (L3-hot) with AV staging aliased into the dead Sc region.
__global__ __launch_bounds__(512, 4) void k2_new(const float* __restrict__ Q,
                                                 const float* __restrict__ AK,
                                                 const float* __restrict__ AV,
                                                 u16* __restrict__ qkb,
                                                 float* __restrict__ invg,
                                                 float* __restrict__ attn,
                                                 float* __restrict__ outp) {
    __shared__ __align__(16) u16 Sc[64 * 512];    // 64 KB (phase A rel; phase B AV staging alias)
    __shared__ __align__(16) u16 QsAk[64][72];    // Qs, then Ak staging (9 KB)
    __shared__ float invs[64];
    const float SCL = 0.18033688011112042f;  // log2(e)/8
    const int q = blockIdx.x;
    const int t = threadIdx.x;
    const int l = t & 63, w = t >> 6, lr = l & 15, lg = l >> 4;
    const int wq = w & 3;   // k/d quarter
    const int wh = w >> 2;  // batch half
    const int srow = t >> 3, sc8 = (t & 7) << 3;  // 64-row x 8-col staging map

    {   // Qs (pre-scaled by SCL): row srow, 8 f32
        const float* qp = &Q[((size_t)(srow * S_ + q) << 6) + sc8];
        float4 a = *reinterpret_cast<const float4*>(qp);
        float4 b = *reinterpret_cast<const float4*>(qp + 4);
        *reinterpret_cast<uint4*>(&QsAk[srow][sc8]) =
            make_uint4(pack2(a.x * SCL, a.y * SCL), pack2(a.z * SCL, a.w * SCL),
                       pack2(b.x * SCL, b.y * SCL), pack2(b.z * SCL, b.w * SCL));
    }
    __syncthreads();
    short8 qa[2][2];
#pragma unroll
    for (int bh = 0; bh < 2; ++bh)
#pragma unroll
        for (int h = 0; h < 2; ++h)
            qa[bh][h] = *reinterpret_cast<const short8*>(
                &QsAk[(wh << 5) + (bh << 4) + lr][(h << 5) + (lg << 3)]);
    __syncthreads();   // Qs reads done; QsAk becomes Ak staging

    const float* akbase = &AK[(size_t)q << 16];
    const float* avbase = &AV[(size_t)q << 16];
    float4 pa[2];
    float4 pv[2][2];
#define LDK(tile) do { const float* p_ = akbase + ((size_t)(tile) << 12) + (srow << 6) + sc8; \
        pa[0] = *reinterpret_cast<const float4*>(p_);                                         \
        pa[1] = *reinterpret_cast<const float4*>(p_ + 4); } while (0)
#define STAGEK() do {                                                                   \
        *reinterpret_cast<uint4*>(&QsAk[srow][sc8]) =                                   \
            make_uint4(pack2(pa[0].x, pa[0].y), pack2(pa[0].z, pa[0].w),                \
                       pack2(pa[1].x, pa[1].y), pack2(pa[1].z, pa[1].w)); } while (0)
    LDK(0);
    float ssum = 0.f;

    // ---- phase A + per-half combine: 16 AK tiles, Sc holds one 512-col half
    for (int T = 0; T < 16; ++T) {
        STAGEK();
        __syncthreads();
        if (T < 15) LDK(T + 1);
        short8 ak0 = *reinterpret_cast<const short8*>(&QsAk[(wq << 4) + lr][lg << 3]);
        short8 ak1 = *reinterpret_cast<const short8*>(&QsAk[(wq << 4) + lr][32 + (lg << 3)]);
        int kl = ((T & 7) << 6) + (wq << 4) + (lg << 2);
#pragma unroll
        for (int bh = 0; bh < 2; ++bh) {
            f32x4 c = {};
            c = __builtin_amdgcn_mfma_f32_16x16x32_bf16(ak0, qa[bh][0], c, 0, 0, 0);
            c = __builtin_amdgcn_mfma_f32_16x16x32_bf16(ak1, qa[bh][1], c, 0, 0, 0);
            *reinterpret_cast<uint2*>(&Sc[sidx5((wh << 5) + (bh << 4) + lr, kl)]) =
                make_uint2(pack2(c[0], c[1]), pack2(c[2], c[3]));
        }
        __syncthreads();
        if (T == 15) {   // prefetch AV tiles 0,1 (in flight through final combine)
#pragma unroll
            for (int s = 0; s < 2; ++s)
#pragma unroll
                for (int i = 0; i < 2; ++i) {
                    int f = (i << 9) + t;
                    pv[s][i] = *reinterpret_cast<const float4*>(
                        &avbase[((size_t)s << 12) + ((size_t)(f >> 4) << 6) + ((f & 15) << 2)]);
                }
        }
        if ((T & 7) == 7) {
            // combine half kh: P = exp2(qk + rel) -> global (over qkb); rowsum in regs
            const int kh = T >> 3;
            const int ch = t & 7;
#pragma unroll 4
            for (int i = 0; i < 8; ++i) {
                int klc = (((i << 3) + ch) << 3);
                int kg = (kh << 9) + klc;
                int idx = sidx5(srow, klc);
                ushort8 rel = *reinterpret_cast<const ushort8*>(&Sc[idx]);
                ushort8 gq = *reinterpret_cast<const ushort8*>(
                    &qkb[((size_t)(srow * S_ + q) << 10) + kg]);
                ushort8 e;
#pragma unroll
                for (int jj = 0; jj < 8; ++jj) {
                    float ev = exp2f(bf2f(gq[jj]) + bf2f(rel[jj]));
                    ssum += ev;
                    e[jj] = f2bf(ev);
                }
                *reinterpret_cast<ushort8*>(&qkb[((size_t)(srow * S_ + q) << 10) + kg]) = e;
            }
        }
    }
#undef LDK
#undef STAGEK
    // reduce rowsum (8 threads/row) -> invs + invg
    ssum += __shfl_xor(ssum, 1); ssum += __shfl_xor(ssum, 2); ssum += __shfl_xor(ssum, 4);
    if ((t & 7) == 0) {
        float inv = 1.0f / ssum;
        invs[srow] = inv;
        invg[srow * S_ + q] = inv;
    }
    __syncthreads();   // combine done everywhere; Sc dead -> Akb alias safe

    // ---- phase B: out_rel = (P . a_value[q]) * inv ; attn write folded in.
    u16* Akb = &Sc[0];   // [2][64][72] bf16 AV staging (18 KB) aliased into Sc
    tpose_store_p(Akb, 72, pv[0][0], (w << 2), t);
    tpose_store_p(Akb, 72, pv[0][1], 32 + (w << 2), t);
    __syncthreads();
    f32x4 oacc[2] = {};
#pragma unroll 2
    for (int tt = 0; tt < 16; ++tt) {
        const int cur = tt & 1, nxt = cur ^ 1;
        const u16* Akc = Akb + cur * 4608;
        short8 bb0 = *reinterpret_cast<const short8*>(&Akc[((wq << 4) + lr) * 72 + (lg << 3)]);
        short8 bb1 = *reinterpret_cast<const short8*>(&Akc[((wq << 4) + lr) * 72 + 32 + (lg << 3)]);
        if (tt < 15) {
            tpose_store_p(Akb + nxt * 4608, 72, pv[nxt][0], (w << 2), t);
            tpose_store_p(Akb + nxt * 4608, 72, pv[nxt][1], 32 + (w << 2), t);
        }
        if (tt < 14) {
#pragma unroll
            for (int i = 0; i < 2; ++i) {
                int f = (i << 9) + t;
                pv[cur][i] = *reinterpret_cast<const float4*>(
                    &avbase[((size_t)(tt + 2) << 12) + ((size_t)(f >> 4) << 6) + ((f & 15) << 2)]);
            }
        }
        // attn write: rows 4tt..4tt+3 (reads P from global, L2/L3-hot, coalesced)
        {
            int col = (t & 255) << 2;
#pragma unroll
            for (int rr = 0; rr < 2; ++rr) {
                int row = (tt << 2) + (rr << 1) + (t >> 8);
                uint2 u = *reinterpret_cast<const uint2*>(
                    &qkb[((size_t)(row * S_ + q) << 10) + col]);
                float inv = invs[row];
                float4 o = make_float4(bf2f((u16)(u.x & 0xffff)) * inv,
                                       bf2f((u16)(u.x >> 16)) * inv,
                                       bf2f((u16)(u.y & 0xffff)) * inv,
                                       bf2f((u16)(u.y >> 16)) * inv);
                *reinterpret_cast<float4*>(&attn[((size_t)(row * S_ + q) << 10) + col]) = o;
            }
        }
#pragma unroll
        for (int mi = 0; mi < 2; ++mi) {
            const u16* prow = &qkb[((size_t)(((wh << 5) + (mi << 4) + lr) * S_ + q) << 10)
                                   + (tt << 6) + (lg << 3)];
            short8 ea0 = *reinterpret_cast<const short8*>(prow);
            short8 ea1 = *reinterpret_cast<const short8*>(prow + 32);
            oacc[mi] = __builtin_amdgcn_mfma_f32_16x16x32_bf16(ea0, bb0, oacc[mi], 0, 0, 0);
            oacc[mi] = __builtin_amdgcn_mfma_f32_16x16x32_bf16(ea1, bb1, oacc[mi], 0, 0, 0);
        }
        __syncthreads();
    }
#pragma unroll
    for (int mi = 0; mi < 2; ++mi)
#pragma unroll
        for (int r = 0; r < 4; ++r) {
            int brow = (wh << 5) + (mi << 4) + (lg << 2) + r;
            outp[((size_t)(brow * S_ + q) << 6) + (wq << 4) + lr] = oacc[mi][r] * invs[brow];
        }
}

// ---------------- K2 fallback (f32 qk in attn region), R12-structure
__global__ __launch_bounds__(512) void k2_f32(const float* __restrict__ Q,
                                              const float* __restrict__ AK,
                                              const float* __restrict__ AV,
                                              const float* __restrict__ qkf,
                                              float* __restrict__ attn,
                                              float* __restrict__ outp) {
    __shared__ __align__(16) u16 Sc[64 * 1024];
    __shared__ __align__(16) u16 Qs[64][72];
    __shared__ __align__(16) u16 Ak[2][64][72];
    __shared__ float invs[64];
    const float SCL = 0.18033688011112042f;
    const int q = blockIdx.x;
    const int t = threadIdx.x;
    const int l = t & 63, w = t >> 6, lr = l & 15, lg = l >> 4;
    const int wq = w & 3, wh = w >> 2;
    const int srow = t >> 3, sc8 = (t & 7) << 3;
    {
        const float* qp = &Q[((size_t)(srow * S_ + q) << 6) + sc8];
        float4 a = *reinterpret_cast<const float4*>(qp);
        float4 b = *reinterpret_cast<const float4*>(qp + 4);
        *reinterpret_cast<uint4*>(&Qs[srow][sc8]) =
            make_uint4(pack2(a.x * SCL, a.y * SCL), pack2(a.z * SCL, a.w * SCL),
                       pack2(b.x * SCL, b.y * SCL), pack2(b.z * SCL, b.w * SCL));
    }
    const float* akbase = &AK[(size_t)q << 16];
    float4 pa[2][2];
#define LDK(set, tile) do { const float* p_ = akbase + ((size_t)(tile) << 12) + (srow << 6) + sc8; \
        pa[set][0] = *reinterpret_cast<const float4*>(p_);                                         \
        pa[set][1] = *reinterpret_cast<const float4*>(p_ + 4); } while (0)
#define STAGEK(buf) do {                                                                     \
        *reinterpret_cast<uint4*>(&Ak[buf][srow][sc8]) =                                     \
            make_uint4(pack2(pa[buf][0].x, pa[buf][0].y), pack2(pa[buf][0].z, pa[buf][0].w), \
                       pack2(pa[buf][1].x, pa[buf][1].y), pack2(pa[buf][1].z, pa[buf][1].w)); } while (0)
    LDK(0, 0); LDK(1, 1);
    __syncthreads();
    short8 qa[2][2];
#pragma unroll
    for (int bh = 0; bh < 2; ++bh)
#pragma unroll
        for (int h = 0; h < 2; ++h)
            qa[bh][h] = *reinterpret_cast<const short8*>(
                &Qs[(wh << 5) + (bh << 4) + lr][(h << 5) + (lg << 3)]);
    STAGEK(0);
    __syncthreads();
#pragma unroll 2
    for (int tt = 0; tt < 16; ++tt) {
        const int cur = tt & 1, nxt = cur ^ 1;
        short8 ak0 = *reinterpret_cast<const short8*>(&Ak[cur][(wq << 4) + lr][lg << 3]);
        short8 ak1 = *reinterpret_cast<const short8*>(&Ak[cur][(wq << 4) + lr][32 + (lg << 3)]);
        if (tt < 15) STAGEK(nxt);
        if (tt < 14) LDK(cur, tt + 2);
        int kbase = (tt << 6) + (wq << 4) + (lg << 2);
#pragma unroll
        for (int bh = 0; bh < 2; ++bh) {
            f32x4 c = {};
            c = __builtin_amdgcn_mfma_f32_16x16x32_bf16(ak0, qa[bh][0], c, 0, 0, 0);
            c = __builtin_amdgcn_mfma_f32_16x16x32_bf16(ak1, qa[bh][1], c, 0, 0, 0);
            *reinterpret_cast<uint2*>(&Sc[scidx((wh << 5) + (bh << 4) + lr, kbase)]) =
                make_uint2(pack2(c[0], c[1]), pack2(c[2], c[3]));
        }
        __syncthreads();
    }
#undef LDK
#undef STAGEK
    const float* avbase = &AV[(size_t)q << 16];
    float4 pv[2][2];
#pragma unroll
    for (int s = 0; s < 2; ++s)
#pragma unroll
        for (int i = 0; i < 2; ++i) {
            int f = (i << 9) + t;
            pv[s][i] = *reinterpret_cast<const float4*>(
                &avbase[((size_t)s << 12) + ((size_t)(f >> 4) << 6) + ((f & 15) << 2)]);
        }
    {
        const int ch = t & 7;
        float s = 0.f;
#pragma unroll 4
        for (int i = 0; i < 16; ++i) {
            int k = (((i << 3) + ch) << 3);
            int idx = scidx(srow, k);
            ushort8 rel = *reinterpret_cast<const ushort8*>(&Sc[idx]);
            const float* qkrow = &qkf[((size_t)(srow * S_ + q) << 10)];
            float4 g0 = *reinterpret_cast<const float4*>(&qkrow[k]);
            float4 g1 = *reinterpret_cast<const float4*>(&qkrow[k + 4]);
            float g[8] = {g0.x, g0.y, g0.z, g0.w, g1.x, g1.y, g1.z, g1.w};
            ushort8 e;
#pragma unroll
            for (int jj = 0; jj < 8; ++jj) {
                float ev = exp2f(g[jj] + bf2f(rel[jj]));
                s += ev;
                e[jj] = f2bf(ev);
            }
            *reinterpret_cast<ushort8*>(&Sc[idx]) = e;
        }
        s += __shfl_xor(s, 1); s += __shfl_xor(s, 2); s += __shfl_xor(s, 4);
        if (ch == 0) invs[srow] = 1.0f / s;
    }
    __syncthreads();
    tpose_store_p(&Ak[0][0][0], 72, pv[0][0], (w << 2), t);
    tpose_store_p(&Ak[0][0][0], 72, pv[0][1], 32 + (w << 2), t);
    __syncthreads();
    f32x4 oacc[2] = {};
#pragma unroll 2
    for (int tt = 0; tt < 16; ++tt) {
        const int cur = tt & 1, nxt = cur ^ 1;
        short8 bb0 = *reinterpret_cast<const short8*>(&Ak[cur][(wq << 4) + lr][lg << 3]);
        short8 bb1 = *reinterpret_cast<const short8*>(&Ak[cur][(wq << 4) + lr][32 + (lg << 3)]);
        if (tt < 15) {
            tpose_store_p(&Ak[nxt][0][0], 72, pv[nxt][0], (w << 2), t);
            tpose_store_p(&Ak[nxt][0][0], 72, pv[nxt][1], 32 + (w << 2), t);
        }
        if (tt < 14) {
#pragma unroll
            for (int i = 0; i < 2; ++i) {
                int f = (i << 9) + t;
                pv[cur][i] = *reinterpret_cast<const float4*>(
                    &avbase[((size_t)(tt + 2) << 12) + ((size_t)(f >> 4) << 6) + ((f & 15) << 2)]);
            }
        }
        {
            int col = (t & 255) << 2;
#pragma unroll
            for (int rr = 0; rr < 2; ++rr) {
                int row = (tt << 2) + (rr << 1) + (t >> 8);
                uint2 u = *reinterpret_cast<const uint2*>(&Sc[scidx(row, col)]);
                float inv = invs[row];
                float4 o = make_float4(bf2f((u16)(u.x & 0xffff)) * inv,
                                       bf2f((u16)(u.x >> 16)) * inv,
                                       bf2f((u16)(u.y & 0xffff)) * inv,
                                       bf2f((u16)(u.y >> 16)) * inv);
                *reinterpret_cast<float4*>(&attn[((size_t)(row * S_ + q) << 10) + col]) = o;
            }
        }
#pragma unroll
        for (int mi = 0; mi < 2; ++mi) {
            short8 ea0 = *reinterpret_cast<const short8*>(
                &Sc[scidx((wh << 5) + (mi << 4) + lr, (tt << 6) + (lg << 3))]);
            short8 ea1 = *reinterpret_cast<const short8*>(
                &Sc[scidx((wh << 5) + (mi << 4) + lr, (tt << 6) + 32 + (lg << 3))]);
            oacc[mi] = __builtin_amdgcn_mfma_f32_16x16x32_bf16(ea0, bb0, oacc[mi], 0, 0, 0);
            oacc[mi] = __builtin_amdgcn_mfma_f32_16x16x32_bf16(ea1, bb1, oacc[mi], 0, 0, 0);
        }
        __syncthreads();
    }
#pragma unroll
    for (int mi = 0; mi < 2; ++mi)
#pragma unroll
        for (int r = 0; r < 4; ++r) {
            int brow = (wh << 5) + (mi << 4) + (lg << 2) + r;
            outp[((size_t)(brow * S_ + q) << 6) + (wq << 4) + lr] = oacc[mi][r] * invs[brow];
        }
}

// ---------------- K3: out += (P.V)*inv ; WS=1 reads P bf16 frags, barrier-free loop
template <int WS>
__global__ __launch_bounds__(512) void k3_pv(const float* __restrict__ V,
                                             const float* __restrict__ attn,
                                             const u16* __restrict__ P,
                                             const float* __restrict__ invg,
                                             float* __restrict__ outp) {
    __shared__ __align__(16) u16 Vt[64 * 1032];   // V^T bf16, pitch 1032
    __shared__ __align__(16) u16 At[2][64][72];   // WS=0 staging only
    const int b  = blockIdx.x >> 2;
    const int qq = blockIdx.x & 3;
    const int t  = threadIdx.x;
    const int l = t & 63, w = t >> 6, lr = l & 15, lg = l >> 4;
    const int wq = w & 3;
    const int dh = w >> 2;
    const int srow = t >> 3, sc8 = (t & 7) << 3;

    for (int kt = 0; kt < 16; ++kt) {
#pragma unroll
        for (int i = 0; i < 2; ++i) {
            int f = (i << 9) + t;
            int row = f >> 4, c = (f & 15) << 2;
            float4 pvv = *reinterpret_cast<const float4*>(
                &V[((size_t)(b * S_ + (kt << 6) + row) << 6) + c]);
            tpose_store_p(&Vt[0], 1032, pvv, (kt << 6) + (i << 5) + (w << 2), t);
        }
    }
    __syncthreads();

    for (int qs = 0; qs < 4; ++qs) {
        const int qsbase = (qq << 8) + (qs << 6);
        f32x4 acc[2] = {};
        if (WS) {
            const u16* prow = &P[((size_t)(b * S_ + qsbase + (wq << 4) + lr) << 10) + (lg << 3)];
            short8 a0b[2], a1b[2];
#define LDPB(buf, kt) do { const u16* p_ = prow + ((kt) << 6);              \
            a0b[buf] = *reinterpret_cast<const short8*>(p_);                \
            a1b[buf] = *reinterpret_cast<const short8*>(p_ + 32); } while (0)
            LDPB(0, 0); LDPB(1, 1);
#pragma unroll 2
            for (int kt = 0; kt < 16; ++kt) {
                const int buf = kt & 1;
                short8 a0 = a0b[buf], a1 = a1b[buf];
                if (kt < 14) LDPB(buf, kt + 2);
#pragma unroll
                for (int n = 0; n < 2; ++n) {
                    const u16* vb = &Vt[((dh << 5) + (n << 4) + lr) * 1032 + (kt << 6) + (lg << 3)];
                    short8 b0 = *reinterpret_cast<const short8*>(vb);
                    short8 b1 = *reinterpret_cast<const short8*>(vb + 32);
                    acc[n] = __builtin_amdgcn_mfma_f32_16x16x32_bf16(a0, b0, acc[n], 0, 0, 0);
                    acc[n] = __builtin_amdgcn_mfma_f32_16x16x32_bf16(a1, b1, acc[n], 0, 0, 0);
                }
            }
#undef LDPB
            float4 inv4 = *reinterpret_cast<const float4*>(
                &invg[b * S_ + qsbase + (wq << 4) + (lg << 2)]);
            float invr[4] = {inv4.x, inv4.y, inv4.z, inv4.w};
#pragma unroll
            for (int n = 0; n < 2; ++n)
#pragma unroll
                for (int r = 0; r < 4; ++r) {
                    size_t idx = ((size_t)(b * S_ + qsbase + (wq << 4) + (lg << 2) + r) << 6)
                                 + (dh << 5) + (n << 4) + lr;
                    outp[idx] += acc[n][r] * invr[r];
                }
        } else {
            const float* arow = &attn[((size_t)(b * S_ + qsbase + srow) << 10) + sc8];
            float4 pa[2][2];
#define LDA3(set, tile) do { const float* p_ = arow + ((tile) << 6);       \
            pa[set][0] = *reinterpret_cast<const float4*>(p_);             \
            pa[set][1] = *reinterpret_cast<const float4*>(p_ + 4); } while (0)
#define STAGEA(buf) do {                                                                     \
            *reinterpret_cast<uint4*>(&At[buf][srow][sc8]) =                                 \
                make_uint4(pack2(pa[buf][0].x, pa[buf][0].y), pack2(pa[buf][0].z, pa[buf][0].w), \
                           pack2(pa[buf][1].x, pa[buf][1].y), pack2(pa[buf][1].z, pa[buf][1].w)); } while (0)
            LDA3(0, 0); LDA3(1, 1);
            __syncthreads();
            STAGEA(0);
            __syncthreads();
#pragma unroll 2
            for (int kt = 0; kt < 16; ++kt) {
                const int cur = kt & 1, nxt = cur ^ 1;
                short8 a0 = *reinterpret_cast<const short8*>(&At[cur][(wq << 4) + lr][lg << 3]);
                short8 a1 = *reinterpret_cast<const short8*>(&At[cur][(wq << 4) + lr][32 + (lg << 3)]);
                if (kt < 15) STAGEA(nxt);
                if (kt < 14) LDA3(cur, kt + 2);
#pragma unroll
                for (int n = 0; n < 2; ++n) {
                    const u16* vb = &Vt[((dh << 5) + (n << 4) + lr) * 1032 + (kt << 6) + (lg << 3)];
                    short8 b0 = *reinterpret_cast<const short8*>(vb);
                    short8 b1 = *reinterpret_cast<const short8*>(vb + 32);
                    acc[n] = __builtin_amdgcn_mfma_f32_16x16x32_bf16(a0, b0, acc[n], 0, 0, 0);
                    acc[n] = __builtin_amdgcn_mfma_f32_16x16x32_bf16(a1, b1, acc[n], 0, 0, 0);
                }
                __syncthreads();
            }
#undef LDA3
#undef STAGEA
#pragma unroll
            for (int n = 0; n < 2; ++n)
#pragma unroll
                for (int r = 0; r < 4; ++r) {
                    size_t idx = ((size_t)(b * S_ + qsbase + (wq << 4) + (lg << 2) + r) << 6)
                                 + (dh << 5) + (n << 4) + lr;
                    outp[idx] += acc[n][r];
                }
        }
    }
}

extern "C" void kernel_launch(void* const* d_in, const int* in_sizes, int n_in,
                              void* d_out, int out_size, void* d_ws, size_t ws_size,
                              hipStream_t stream) {
    (void)in_sizes; (void)n_in; (void)out_size;
    const float* Q  = (const float*)d_in[0];
    const float* K  = (const float*)d_in[1];
    const float* V  = (const float*)d_in[2];
    const float* AK = (const float*)d_in[3];
    const float* AV = (const float*)d_in[4];
    float* outp = (float*)d_out;
    float* attn = outp + (size_t)B_ * S_ * D_;
    u16*   qkb  = (u16*)d_ws;
    float* invg = (float*)(qkb + (size_t)B_ * S_ * S_);
    const size_t need = (size_t)B_ * S_ * S_ * sizeof(u16)     // 128 MB P/qk
                      + (size_t)B_ * S_ * sizeof(float);       // 256 KB invg

    if (ws_size >= need) {
        k1_qk<1><<<dim3(64 * 8 * 8), dim3(256), 0, stream>>>(Q, K, attn, qkb);
        k2_new  <<<dim3(1024),       dim3(512), 0, stream>>>(Q, AK, AV, qkb, invg, attn, outp);
        k3_pv<1><<<dim3(256),        dim3(512), 0, stream>>>(V, attn, qkb, invg, outp);
    } else {
        k1_qk<0><<<dim3(64 * 8 * 8), dim3(256), 0, stream>>>(Q, K, attn, qkb);
        k2_f32  <<<dim3(1024),       dim3(512), 0, stream>>>(Q, AK, AV, attn, attn, outp);
        k3_pv<0><<<dim3(256),        dim3(512), 0, stream>>>(V, attn, qkb, invg, outp);
    }
}

// Round 18
// 342.811 us; speedup vs baseline: 1.1354x; 1.1354x over previous
//
#include <hip/hip_runtime.h>
#include <stdint.h>

#define S_ 1024
#define D_ 64
#define B_ 64

typedef short short8 __attribute__((ext_vector_type(8)));
typedef unsigned short ushort8 __attribute__((ext_vector_type(8)));
typedef float f32x4 __attribute__((ext_vector_type(4)));
typedef unsigned short u16;

__device__ __forceinline__ u16 f2bf(float x) {
    uint32_t u = __builtin_bit_cast(uint32_t, x);
    return (u16)((u + 0x7FFFu + ((u >> 16) & 1u)) >> 16);
}
__device__ __forceinline__ float bf2f(u16 b) {
    return __builtin_bit_cast(float, ((uint32_t)b) << 16);
}
__device__ __forceinline__ uint32_t pack2(float a, float b) {
    return (uint32_t)f2bf(a) | ((uint32_t)f2bf(b) << 16);
}
// XOR-swizzled index into the row x 1024 bf16 score buffer (16B-chunk swizzle by row&15)
__device__ __forceinline__ int scidx(int row, int k) {
    return (((row << 10) + (k & ~7)) ^ ((row & 15) << 3)) + (k & 7);
}

// ---------------- K1: qk[b,q,k] = (Q.K)*SCL -> bf16 ws (WS) or f32 attn region
template <int WS>
__global__ __launch_bounds__(256) void k1_qk(const float* __restrict__ Q,
                                             const float* __restrict__ Kk,
                                             float* __restrict__ qkf,
                                             u16* __restrict__ qkb) {
    __shared__ __align__(16) u16 Qs[128][72];
    __shared__ __align__(16) u16 Ks[128][72];
    const float SCL = 0.18033688011112042f;  // log2(e)/8
    const int bx = blockIdx.x;
    const int b  = bx >> 6;
    const int q0 = ((bx >> 3) & 7) << 7;
    const int k0 = (bx & 7) << 7;
    const int t  = threadIdx.x;
#pragma unroll
    for (int i = 0; i < 8; ++i) {
        int f = (i << 8) + t;
        int row = f >> 4, c = (f & 15) << 2;
        float4 v = *reinterpret_cast<const float4*>(&Q[((size_t)(b * S_ + q0 + row) << 6) + c]);
        *reinterpret_cast<uint2*>(&Qs[row][c]) = make_uint2(pack2(v.x, v.y), pack2(v.z, v.w));
        float4 u = *reinterpret_cast<const float4*>(&Kk[((size_t)(b * S_ + k0 + row) << 6) + c]);
        *reinterpret_cast<uint2*>(&Ks[row][c]) = make_uint2(pack2(u.x, u.y), pack2(u.z, u.w));
    }
    __syncthreads();
    const int l = t & 63, w = t >> 6, lr = l & 15, lg = l >> 4;
    short8 a[2][2];
#pragma unroll
    for (int mi = 0; mi < 2; ++mi)
#pragma unroll
        for (int h = 0; h < 2; ++h)
            a[mi][h] = *reinterpret_cast<const short8*>(&Qs[((w * 2 + mi) << 4) + lr][h * 32 + lg * 8]);
    f32x4 acc[2][8] = {};
#pragma unroll
    for (int n = 0; n < 8; ++n) {
        short8 b0 = *reinterpret_cast<const short8*>(&Ks[(n << 4) + lr][lg * 8]);
        short8 b1 = *reinterpret_cast<const short8*>(&Ks[(n << 4) + lr][32 + lg * 8]);
#pragma unroll
        for (int mi = 0; mi < 2; ++mi) {
            acc[mi][n] = __builtin_amdgcn_mfma_f32_16x16x32_bf16(a[mi][0], b0, acc[mi][n], 0, 0, 0);
            acc[mi][n] = __builtin_amdgcn_mfma_f32_16x16x32_bf16(a[mi][1], b1, acc[mi][n], 0, 0, 0);
        }
    }
#pragma unroll
    for (int mi = 0; mi < 2; ++mi)
#pragma unroll
        for (int n = 0; n < 8; ++n)
#pragma unroll
            for (int r = 0; r < 4; ++r) {
                int qq = q0 + ((w * 2 + mi) << 4) + (lg << 2) + r;
                int kc = k0 + (n << 4) + lr;
                size_t idx = ((size_t)(b * S_ + qq) << 10) + kc;
                if (WS) qkb[idx] = f2bf(acc[mi][n][r] * SCL);
                else    qkf[idx] = acc[mi][n][r] * SCL;
            }
}

// in-register 4x4 transpose (lanes l, l^16, l^32, l^48) then b64 store: T[d][kb..kb+3]
__device__ __forceinline__ void tpose_store_p(u16* Tls, int pitch, float4 p,
                                              int kb, int t) {
    const int l = t & 63, lr = l & 15, lg = l >> 4;
    float v0 = p.x, v1 = p.y, v2 = p.z, v3 = p.w;
    float y0 = __shfl_xor(v0, 16), y1 = __shfl_xor(v1, 16),
          y2 = __shfl_xor(v2, 16), y3 = __shfl_xor(v3, 16);
    bool o = (lg & 1);
    float n0 = o ? y1 : v0, n1 = o ? v1 : y0, n2 = o ? y3 : v2, n3 = o ? v3 : y2;
    float z0 = __shfl_xor(n0, 32), z1 = __shfl_xor(n1, 32),
          z2 = __shfl_xor(n2, 32), z3 = __shfl_xor(n3, 32);
    bool h = (lg & 2);
    float T0 = h ? z2 : n0, T1 = h ? z3 : n1, T2 = h ? n2 : z0, T3 = h ? n3 : z1;
    int d = (lr << 2) + lg;
    *reinterpret_cast<uint2*>(&Tls[d * pitch + kb]) = make_uint2(pack2(T0, T1), pack2(T2, T3));
}

// ---------------- K2: one block per q, all 64 batches, 512 threads
// WS=1: writes attn f32 (phase B, overlapped) AND unnormalized P bf16 over qkb + invg.
template <int WS>
__global__ __launch_bounds__(512) void k2_mid(const float* __restrict__ Q,
                                              const float* __restrict__ AK,
                                              const float* __restrict__ AV,
                                              u16* __restrict__ qkb,
                                              const float* __restrict__ qkf,
                                              float* __restrict__ invg,
                                              float* __restrict__ attn,
                                              float* __restrict__ outp) {
    __shared__ __align__(16) u16 Sc[64 * 1024];     // 128 KB
    __shared__ __align__(16) u16 Qs[64][72];
    __shared__ __align__(16) u16 Ak[2][64][72];     // double-buffered
    __shared__ float invs[64];
    const float SCL = 0.18033688011112042f;  // log2(e)/8
    const int q = blockIdx.x;
    const int t = threadIdx.x;
    const int l = t & 63, w = t >> 6, lr = l & 15, lg = l >> 4;
    const int wq = w & 3;   // k/d quarter
    const int wh = w >> 2;  // batch half
    const int srow = t >> 3, sc8 = (t & 7) << 3;  // 64-row x 8-col staging map

    {   // Qs (pre-scaled by SCL): row srow, 8 f32
        const float* qp = &Q[((size_t)(srow * S_ + q) << 6) + sc8];
        float4 a = *reinterpret_cast<const float4*>(qp);
        float4 b = *reinterpret_cast<const float4*>(qp + 4);
        *reinterpret_cast<uint4*>(&Qs[srow][sc8]) =
            make_uint4(pack2(a.x * SCL, a.y * SCL), pack2(a.z * SCL, a.w * SCL),
                       pack2(b.x * SCL, b.y * SCL), pack2(b.z * SCL, b.w * SCL));
    }
    const float* akbase = &AK[(size_t)q << 16];
    float4 pa[2][2];
#define LDK(set, tile) do { const float* p_ = akbase + ((size_t)(tile) << 12) + (srow << 6) + sc8; \
        pa[set][0] = *reinterpret_cast<const float4*>(p_);                                         \
        pa[set][1] = *reinterpret_cast<const float4*>(p_ + 4); } while (0)
#define STAGEK(buf) do {                                                                     \
        *reinterpret_cast<uint4*>(&Ak[buf][srow][sc8]) =                                     \
            make_uint4(pack2(pa[buf][0].x, pa[buf][0].y), pack2(pa[buf][0].z, pa[buf][0].w), \
                       pack2(pa[buf][1].x, pa[buf][1].y), pack2(pa[buf][1].z, pa[buf][1].w)); } while (0)
    LDK(0, 0); LDK(1, 1);
    __syncthreads();   // Qs ready
    short8 qa[2][2];
#pragma unroll
    for (int bh = 0; bh < 2; ++bh)
#pragma unroll
        for (int h = 0; h < 2; ++h)
            qa[bh][h] = *reinterpret_cast<const short8*>(
                &Qs[(wh << 5) + (bh << 4) + lr][(h << 5) + (lg << 3)]);
    STAGEK(0);
    __syncthreads();

    // ---- phase A: Sc[batch][k] = AKtile . (Q*SCL)^T  (1 barrier/tile, dbuf)
#pragma unroll 2
    for (int tt = 0; tt < 16; ++tt) {
        const int cur = tt & 1, nxt = cur ^ 1;
        short8 ak0 = *reinterpret_cast<const short8*>(&Ak[cur][(wq << 4) + lr][lg << 3]);
        short8 ak1 = *reinterpret_cast<const short8*>(&Ak[cur][(wq << 4) + lr][32 + (lg << 3)]);
        if (tt < 15) STAGEK(nxt);
        if (tt < 14) LDK(cur, tt + 2);
        int kbase = (tt << 6) + (wq << 4) + (lg << 2);
#pragma unroll
        for (int bh = 0; bh < 2; ++bh) {
            f32x4 c = {};
            c = __builtin_amdgcn_mfma_f32_16x16x32_bf16(ak0, qa[bh][0], c, 0, 0, 0);
            c = __builtin_amdgcn_mfma_f32_16x16x32_bf16(ak1, qa[bh][1], c, 0, 0, 0);
            *reinterpret_cast<uint2*>(&Sc[scidx((wh << 5) + (bh << 4) + lr, kbase)]) =
                make_uint2(pack2(c[0], c[1]), pack2(c[2], c[3]));
        }
        __syncthreads();
    }
#undef LDK
#undef STAGEK

    // prefetch AV tiles 0,1 (in flight through combine)
    const float* avbase = &AV[(size_t)q << 16];
    float4 pv[2][2];
#pragma unroll
    for (int s = 0; s < 2; ++s)
#pragma unroll
        for (int i = 0; i < 2; ++i) {
            int f = (i << 9) + t;
            pv[s][i] = *reinterpret_cast<const float4*>(
                &avbase[((size_t)s << 12) + ((size_t)(f >> 4) << 6) + ((f & 15) << 2)]);
        }

    // ---- combine + rowsum: P = exp2(qk_scaled + rel); row srow, 8 threads/row
    // WS=1: also write unnormalized P (bf16) back over qkb + invg.
    {
        const int ch = t & 7;
        float s = 0.f;
#pragma unroll 4
        for (int i = 0; i < 16; ++i) {
            int k = (((i << 3) + ch) << 3);
            int idx = scidx(srow, k);
            ushort8 rel = *reinterpret_cast<const ushort8*>(&Sc[idx]);
            float g[8];
            if (WS) {
                ushort8 gq = *reinterpret_cast<const ushort8*>(
                    &qkb[((size_t)(srow * S_ + q) << 10) + k]);
#pragma unroll
                for (int jj = 0; jj < 8; ++jj) g[jj] = bf2f(gq[jj]);
            } else {
                const float* qkrow = &qkf[((size_t)(srow * S_ + q) << 10)];
                float4 g0 = *reinterpret_cast<const float4*>(&qkrow[k]);
                float4 g1 = *reinterpret_cast<const float4*>(&qkrow[k + 4]);
                g[0] = g0.x; g[1] = g0.y; g[2] = g0.z; g[3] = g0.w;
                g[4] = g1.x; g[5] = g1.y; g[6] = g1.z; g[7] = g1.w;
            }
            ushort8 e;
#pragma unroll
            for (int jj = 0; jj < 8; ++jj) {
                float ev = exp2f(g[jj] + bf2f(rel[jj]));
                s += ev;
                e[jj] = f2bf(ev);
            }
            *reinterpret_cast<ushort8*>(&Sc[idx]) = e;
            if (WS)
                *reinterpret_cast<ushort8*>(&qkb[((size_t)(srow * S_ + q) << 10) + k]) = e;
        }
        s += __shfl_xor(s, 1); s += __shfl_xor(s, 2); s += __shfl_xor(s, 4);
        if (ch == 0) {
            float inv = 1.0f / s;
            invs[srow] = inv;
            if (WS) invg[srow * S_ + q] = inv;
        }
    }
    __syncthreads();

    // ---- phase B prologue: stage AV tile 0 into Ak[0]
    tpose_store_p(&Ak[0][0][0], 72, pv[0][0], (w << 2), t);
    tpose_store_p(&Ak[0][0][0], 72, pv[0][1], 32 + (w << 2), t);
    __syncthreads();

    // ---- phase B (+ attn writes folded in): out_rel = (P . a_value[q]) * inv
    f32x4 oacc[2] = {};
#pragma unroll 2
    for (int tt = 0; tt < 16; ++tt) {
        const int cur = tt & 1, nxt = cur ^ 1;
        short8 bb0 = *reinterpret_cast<const short8*>(&Ak[cur][(wq << 4) + lr][lg << 3]);
        short8 bb1 = *reinterpret_cast<const short8*>(&Ak[cur][(wq << 4) + lr][32 + (lg << 3)]);
        if (tt < 15) {
            tpose_store_p(&Ak[nxt][0][0], 72, pv[nxt][0], (w << 2), t);
            tpose_store_p(&Ak[nxt][0][0], 72, pv[nxt][1], 32 + (w << 2), t);
        }
        if (tt < 14) {
#pragma unroll
            for (int i = 0; i < 2; ++i) {
                int f = (i << 9) + t;
                pv[cur][i] = *reinterpret_cast<const float4*>(
                    &avbase[((size_t)(tt + 2) << 12) + ((size_t)(f >> 4) << 6) + ((f & 15) << 2)]);
            }
        }
        // attn write: rows 4tt..4tt+3, fully coalesced (wave covers 1KB runs)
        {
            int col = (t & 255) << 2;
#pragma unroll
            for (int rr = 0; rr < 2; ++rr) {
                int row = (tt << 2) + (rr << 1) + (t >> 8);
                uint2 u = *reinterpret_cast<const uint2*>(&Sc[scidx(row, col)]);
                float inv = invs[row];
                float4 o = make_float4(bf2f((u16)(u.x & 0xffff)) * inv,
                                       bf2f((u16)(u.x >> 16)) * inv,
                                       bf2f((u16)(u.y & 0xffff)) * inv,
                                       bf2f((u16)(u.y >> 16)) * inv);
                *reinterpret_cast<float4*>(&attn[((size_t)(row * S_ + q) << 10) + col]) = o;
            }
        }
#pragma unroll
        for (int mi = 0; mi < 2; ++mi) {
            short8 ea0 = *reinterpret_cast<const short8*>(
                &Sc[scidx((wh << 5) + (mi << 4) + lr, (tt << 6) + (lg << 3))]);
            short8 ea1 = *reinterpret_cast<const short8*>(
                &Sc[scidx((wh << 5) + (mi << 4) + lr, (tt << 6) + 32 + (lg << 3))]);
            oacc[mi] = __builtin_amdgcn_mfma_f32_16x16x32_bf16(ea0, bb0, oacc[mi], 0, 0, 0);
            oacc[mi] = __builtin_amdgcn_mfma_f32_16x16x32_bf16(ea1, bb1, oacc[mi], 0, 0, 0);
        }
        __syncthreads();
    }
#pragma unroll
    for (int mi = 0; mi < 2; ++mi)
#pragma unroll
        for (int r = 0; r < 4; ++r) {
            int brow = (wh << 5) + (mi << 4) + (lg << 2) + r;
            outp[((size_t)(brow * S_ + q) << 6) + (wq << 4) + lr] = oacc[mi][r] * invs[brow];
        }
}

// ---------------- K3: out += (P.V)*inv ; WS=1 reads P bf16 frags, barrier-free loop
template <int WS>
__global__ __launch_bounds__(512) void k3_pv(const float* __restrict__ V,
                                             const float* __restrict__ attn,
                                             const u16* __restrict__ P,
                                             const float* __restrict__ invg,
                                             float* __restrict__ outp) {
    __shared__ __align__(16) u16 Vt[64 * 1032];   // V^T bf16, pitch 1032
    __shared__ __align__(16) u16 At[2][64][72];   // WS=0 staging only
    const int b  = blockIdx.x >> 2;
    const int qq = blockIdx.x & 3;
    const int t  = threadIdx.x;
    const int l = t & 63, w = t >> 6, lr = l & 15, lg = l >> 4;
    const int wq = w & 3;   // q 16-block within 64-row subtile
    const int dh = w >> 2;  // d half
    const int srow = t >> 3, sc8 = (t & 7) << 3;

    // stage V^T once: 16 k-tiles, transpose via shuffles
    for (int kt = 0; kt < 16; ++kt) {
#pragma unroll
        for (int i = 0; i < 2; ++i) {
            int f = (i << 9) + t;
            int row = f >> 4, c = (f & 15) << 2;
            float4 pvv = *reinterpret_cast<const float4*>(
                &V[((size_t)(b * S_ + (kt << 6) + row) << 6) + c]);
            tpose_store_p(&Vt[0], 1032, pvv, (kt << 6) + (i << 5) + (w << 2), t);
        }
    }
    __syncthreads();   // Vt resident; WS=1 path has no further barriers

    for (int qs = 0; qs < 4; ++qs) {
        const int qsbase = (qq << 8) + (qs << 6);
        f32x4 acc[2] = {};
        if (WS) {
            const u16* prow = &P[((size_t)(b * S_ + qsbase + (wq << 4) + lr) << 10) + (lg << 3)];
            short8 a0b[2], a1b[2];
#define LDPB(buf, kt) do { const u16* p_ = prow + ((kt) << 6);              \
            a0b[buf] = *reinterpret_cast<const short8*>(p_);                \
            a1b[buf] = *reinterpret_cast<const short8*>(p_ + 32); } while (0)
            LDPB(0, 0); LDPB(1, 1);
#pragma unroll 2
            for (int kt = 0; kt < 16; ++kt) {
                const int buf = kt & 1;
                short8 a0 = a0b[buf], a1 = a1b[buf];
                if (kt < 14) LDPB(buf, kt + 2);
#pragma unroll
                for (int n = 0; n < 2; ++n) {
                    const u16* vb = &Vt[((dh << 5) + (n << 4) + lr) * 1032 + (kt << 6) + (lg << 3)];
                    short8 b0 = *reinterpret_cast<const short8*>(vb);
                    short8 b1 = *reinterpret_cast<const short8*>(vb + 32);
                    acc[n] = __builtin_amdgcn_mfma_f32_16x16x32_bf16(a0, b0, acc[n], 0, 0, 0);
                    acc[n] = __builtin_amdgcn_mfma_f32_16x16x32_bf16(a1, b1, acc[n], 0, 0, 0);
                }
            }
#undef LDPB
            float4 inv4 = *reinterpret_cast<const float4*>(
                &invg[b * S_ + qsbase + (wq << 4) + (lg << 2)]);
            float invr[4] = {inv4.x, inv4.y, inv4.z, inv4.w};
#pragma unroll
            for (int n = 0; n < 2; ++n)
#pragma unroll
                for (int r = 0; r < 4; ++r) {
                    size_t idx = ((size_t)(b * S_ + qsbase + (wq << 4) + (lg << 2) + r) << 6)
                                 + (dh << 5) + (n << 4) + lr;
                    outp[idx] += acc[n][r] * invr[r];
                }
        } else {
            const float* arow = &attn[((size_t)(b * S_ + qsbase + srow) << 10) + sc8];
            float4 pa[2][2];
#define LDA3(set, tile) do { const float* p_ = arow + ((tile) << 6);       \
            pa[set][0] = *reinterpret_cast<const float4*>(p_);             \
            pa[set][1] = *reinterpret_cast<const float4*>(p_ + 4); } while (0)
#define STAGEA(buf) do {                                                                     \
            *reinterpret_cast<uint4*>(&At[buf][srow][sc8]) =                                 \
                make_uint4(pack2(pa[buf][0].x, pa[buf][0].y), pack2(pa[buf][0].z, pa[buf][0].w), \
                           pack2(pa[buf][1].x, pa[buf][1].y), pack2(pa[buf][1].z, pa[buf][1].w)); } while (0)
            LDA3(0, 0); LDA3(1, 1);
            __syncthreads();
            STAGEA(0);
            __syncthreads();
#pragma unroll 2
            for (int kt = 0; kt < 16; ++kt) {
                const int cur = kt & 1, nxt = cur ^ 1;
                short8 a0 = *reinterpret_cast<const short8*>(&At[cur][(wq << 4) + lr][lg << 3]);
                short8 a1 = *reinterpret_cast<const short8*>(&At[cur][(wq << 4) + lr][32 + (lg << 3)]);
                if (kt < 15) STAGEA(nxt);
                if (kt < 14) LDA3(cur, kt + 2);
#pragma unroll
                for (int n = 0; n < 2; ++n) {
                    const u16* vb = &Vt[((dh << 5) + (n << 4) + lr) * 1032 + (kt << 6) + (lg << 3)];
                    short8 b0 = *reinterpret_cast<const short8*>(vb);
                    short8 b1 = *reinterpret_cast<const short8*>(vb + 32);
                    acc[n] = __builtin_amdgcn_mfma_f32_16x16x32_bf16(a0, b0, acc[n], 0, 0, 0);
                    acc[n] = __builtin_amdgcn_mfma_f32_16x16x32_bf16(a1, b1, acc[n], 0, 0, 0);
                }
                __syncthreads();
            }
#undef LDA3
#undef STAGEA
#pragma unroll
            for (int n = 0; n < 2; ++n)
#pragma unroll
                for (int r = 0; r < 4; ++r) {
                    size_t idx = ((size_t)(b * S_ + qsbase + (wq << 4) + (lg << 2) + r) << 6)
                                 + (dh << 5) + (n << 4) + lr;
                    outp[idx] += acc[n][r];
                }
        }
    }
}

extern "C" void kernel_launch(void* const* d_in, const int* in_sizes, int n_in,
                              void* d_out, int out_size, void* d_ws, size_t ws_size,
                              hipStream_t stream) {
    (void)in_sizes; (void)n_in; (void)out_size;
    const float* Q  = (const float*)d_in[0];
    const float* K  = (const float*)d_in[1];
    const float* V  = (const float*)d_in[2];
    const float* AK = (const float*)d_in[3];
    const float* AV = (const float*)d_in[4];
    float* outp = (float*)d_out;
    float* attn = outp + (size_t)B_ * S_ * D_;
    u16*   qkb  = (u16*)d_ws;
    float* invg = (float*)(qkb + (size_t)B_ * S_ * S_);
    const size_t need = (size_t)B_ * S_ * S_ * sizeof(u16)     // 128 MB P/qk
                      + (size_t)B_ * S_ * sizeof(float);       // 256 KB invg

    if (ws_size >= need) {
        k1_qk<1> <<<dim3(64 * 8 * 8), dim3(256), 0, stream>>>(Q, K, attn, qkb);
        k2_mid<1><<<dim3(1024),       dim3(512), 0, stream>>>(Q, AK, AV, qkb, attn, invg, attn, outp);
        k3_pv<1> <<<dim3(256),        dim3(512), 0, stream>>>(V, attn, qkb, invg, outp);
    } else {
        k1_qk<0> <<<dim3(64 * 8 * 8), dim3(256), 0, stream>>>(Q, K, attn, qkb);
        k2_mid<0><<<dim3(1024),       dim3(512), 0, stream>>>(Q, AK, AV, qkb, attn, invg, attn, outp);
        k3_pv<0> <<<dim3(256),        dim3(512), 0, stream>>>(V, attn, qkb, invg, outp);
    }
}